// Round 1
// baseline (205.707 us; speedup 1.0000x reference)
//
#include <hip/hip_runtime.h>

// Problem constants (from reference setup_inputs)
#define NB 8
#define LQ 512
#define LC 2048
#define DD 768

typedef _Float16 f16x8 __attribute__((ext_vector_type(8)));
typedef _Float16 f16x4 __attribute__((ext_vector_type(4)));
typedef float    f32x4 __attribute__((ext_vector_type(4)));

// ---------------------------------------------------------------------------
// K0: convert Q fp32 -> Qh [b][q][d] fp16  AND  QhT [b][d][q] fp16
// ---------------------------------------------------------------------------
__global__ __launch_bounds__(256) void preconvert_q(const float* __restrict__ Q,
                                                    _Float16* __restrict__ Qh,
                                                    _Float16* __restrict__ QhT) {
    __shared__ _Float16 lt[64][68];
    const int blk = blockIdx.x;
    const int b   = blk / 96;
    const int rem = blk % 96;
    const int q0  = (rem / 12) * 64;
    const int d0  = (rem % 12) * 64;
    const int t   = threadIdx.x;
    const int tr  = t >> 4;
    const int tc  = t & 15;

    const float* Qb  = Q  + ((size_t)b * LQ + q0) * DD + d0;
    _Float16*    Qhb = Qh + ((size_t)b * LQ + q0) * DD + d0;

#pragma unroll
    for (int i = 0; i < 4; i++) {
        const int row = i * 16 + tr;
        const int col = tc * 4;
        f32x4 v = *(const f32x4*)(Qb + (size_t)row * DD + col);
        f16x4 h;
        h.x = (_Float16)v.x; h.y = (_Float16)v.y;
        h.z = (_Float16)v.z; h.w = (_Float16)v.w;
        *(f16x4*)(Qhb + (size_t)row * DD + col) = h;
        *(f16x4*)&lt[row][col] = h;
    }
    __syncthreads();

    _Float16* QTb = QhT + ((size_t)b * DD + d0) * LQ + q0;
#pragma unroll
    for (int i = 0; i < 4; i++) {
        const int drow = i * 16 + tr;
        const int qc   = tc * 4;
        f16x4 h;
        h.x = lt[qc + 0][drow];
        h.y = lt[qc + 1][drow];
        h.z = lt[qc + 2][drow];
        h.w = lt[qc + 3][drow];
        *(f16x4*)(QTb + (size_t)drow * LQ + qc) = h;
    }
}

// ---------------------------------------------------------------------------
// Main fused kernel v7: barrier-free K-loops.
//
// B-operand MFMA fragments are read DIRECTLY from global (L2-resident Qh/QhT;
// per 16-lane quad-group, 4 lanes cover one full 64B line -> coalesced).
// This removes the Bbuf/Cbuf LDS staging entirely: no per-chunk
// __syncthreads (which drained vmcnt(0) and exposed L2 latency every chunk),
// no 8-way bank-conflicted staging-buffer reads, and LDS drops from 130.5KB
// (1 block/CU) to 50.5KB -> 2 resident blocks (16 waves/CU) under
// __launch_bounds__(512,4).
//
// One WG = (batch, 32 ctx rows), 512 threads (8 waves).
//  - Prologue: stage ctx f32 -> f16 A-tile in ldsA [32][776] (one barrier).
//  - Phase A: S = A @ Qh^T. A-frags from ldsA (2-way conflict = free),
//    B-frags from global Qh. Zero barriers; compiler pipelines vmcnt.
//  - Softmax over q: in-wave shfl reduce + cross-wave via red_max/red_sum
//    (2 barriers). P -> ldsP [32][520] f16 (aliases dead ldsA; safe after X1).
//  - Phase C: awq = P @ Q. A-frags from ldsP, B-frags from global QhT.
//    Zero barriers.
//  - Epilogue: out = ctx(f32, L2-hot) * awq.
// convert_ctx kernel is dropped (ctx converted inline during staging).
// LDS: ldsA [0,49664) | ldsP [0,33280) alias | red [49664,51712). 51712 B.
// ---------------------------------------------------------------------------
#define LDSA_STRIDE 776
#define PSTRIDE     520
#define RED_OFF     49664
#define SMEM_BYTES  51712

__global__ __launch_bounds__(512, 4) void gated_attn(const float* __restrict__ ctx,
                                                     const _Float16* __restrict__ Qh,
                                                     const _Float16* __restrict__ QhT,
                                                     float* __restrict__ out) {
    __shared__ __align__(16) char smem[SMEM_BYTES];
    _Float16* ldsA = (_Float16*)smem;
    _Float16* ldsP = (_Float16*)smem;
    float (*red_max)[32] = (float (*)[32])(smem + RED_OFF);
    float (*red_sum)[32] = (float (*)[32])(smem + RED_OFF + 1024);

    const int b    = blockIdx.x & 7;          // XCD-affine batch
    const int c0   = (blockIdx.x >> 3) * 32;
    const int t    = threadIdx.x;
    const int w    = t >> 6;                  // wave 0..7
    const int lane = t & 63;
    const int quad = lane >> 4;
    const int l15  = lane & 15;

    const float*    Cb  = ctx + ((size_t)b * LC + c0) * DD;
    const _Float16* Qhb = Qh  + (size_t)b * LQ * DD;
    const _Float16* QTb = QhT + (size_t)b * DD * LQ;

    // ---------------- Stage A-tile (ctx f32 -> f16) into ldsA ----------------
#pragma unroll
    for (int i = 0; i < 6; i++) {
        const int idx  = i * 512 + t;
        const int row  = idx / 96;
        const int colc = idx % 96;
        const float* p = Cb + (size_t)row * DD + colc * 8;
        f32x4 f0 = *(const f32x4*)p;
        f32x4 f1 = *(const f32x4*)(p + 4);
        f16x8 v;
        v[0] = (_Float16)f0.x; v[1] = (_Float16)f0.y;
        v[2] = (_Float16)f0.z; v[3] = (_Float16)f0.w;
        v[4] = (_Float16)f1.x; v[5] = (_Float16)f1.y;
        v[6] = (_Float16)f1.z; v[7] = (_Float16)f1.w;
        *(f16x8*)&ldsA[row * LDSA_STRIDE + colc * 8] = v;
    }
    __syncthreads();   // publish ldsA

    // ---------------- Phase A: S = A @ Qh^T (no barriers) ----------------
    f32x4 acc[2][4];
#pragma unroll
    for (int mt = 0; mt < 2; mt++)
#pragma unroll
        for (int nt = 0; nt < 4; nt++)
            acc[mt][nt] = (f32x4){0.f, 0.f, 0.f, 0.f};

    // lane (quad,l15) of wave w reads Qh[q = w*64 + nt*16 + l15][kc*32 + quad*8]
    const _Float16* bqb = Qhb + (size_t)(w * 64 + l15) * DD + quad * 8;
#pragma unroll
    for (int kc = 0; kc < 24; kc++) {
        f16x8 a0 = *(const f16x8*)&ldsA[(size_t)l15        * LDSA_STRIDE + kc * 32 + quad * 8];
        f16x8 a1 = *(const f16x8*)&ldsA[(size_t)(16 + l15) * LDSA_STRIDE + kc * 32 + quad * 8];
#pragma unroll
        for (int nt = 0; nt < 4; nt++) {
            f16x8 bq = *(const f16x8*)(bqb + (size_t)(nt * 16) * DD + kc * 32);
            acc[0][nt] = __builtin_amdgcn_mfma_f32_16x16x32_f16(a0, bq, acc[0][nt], 0, 0, 0);
            acc[1][nt] = __builtin_amdgcn_mfma_f32_16x16x32_f16(a1, bq, acc[1][nt], 0, 0, 0);
        }
    }

    // ---------------- Softmax over q ----------------
    float rm[2][4];
#pragma unroll
    for (int mt = 0; mt < 2; mt++)
#pragma unroll
        for (int r = 0; r < 4; r++)
            rm[mt][r] = -1e30f;
#pragma unroll
    for (int mt = 0; mt < 2; mt++)
#pragma unroll
        for (int nt = 0; nt < 4; nt++) {
            rm[mt][0] = fmaxf(rm[mt][0], acc[mt][nt].x);
            rm[mt][1] = fmaxf(rm[mt][1], acc[mt][nt].y);
            rm[mt][2] = fmaxf(rm[mt][2], acc[mt][nt].z);
            rm[mt][3] = fmaxf(rm[mt][3], acc[mt][nt].w);
        }
#pragma unroll
    for (int off = 1; off < 16; off <<= 1)
#pragma unroll
        for (int mt = 0; mt < 2; mt++)
#pragma unroll
            for (int r = 0; r < 4; r++)
                rm[mt][r] = fmaxf(rm[mt][r], __shfl_xor(rm[mt][r], off));
    if (l15 == 0) {
#pragma unroll
        for (int mt = 0; mt < 2; mt++)
#pragma unroll
            for (int r = 0; r < 4; r++)
                red_max[w][mt * 16 + quad * 4 + r] = rm[mt][r];
    }
    __syncthreads();   // [X1] publish red_max; all ldsA reads drained

    float fm[2][4];
#pragma unroll
    for (int mt = 0; mt < 2; mt++)
#pragma unroll
        for (int r = 0; r < 4; r++) {
            const int row = mt * 16 + quad * 4 + r;
            float m0 = fmaxf(fmaxf(red_max[0][row], red_max[1][row]),
                             fmaxf(red_max[2][row], red_max[3][row]));
            float m1 = fmaxf(fmaxf(red_max[4][row], red_max[5][row]),
                             fmaxf(red_max[6][row], red_max[7][row]));
            fm[mt][r] = fmaxf(m0, m1);
        }
    float rs[2][4];
#pragma unroll
    for (int mt = 0; mt < 2; mt++)
#pragma unroll
        for (int r = 0; r < 4; r++)
            rs[mt][r] = 0.f;
#pragma unroll
    for (int mt = 0; mt < 2; mt++)
#pragma unroll
        for (int nt = 0; nt < 4; nt++) {
            float e0 = __expf(acc[mt][nt].x - fm[mt][0]);
            float e1 = __expf(acc[mt][nt].y - fm[mt][1]);
            float e2 = __expf(acc[mt][nt].z - fm[mt][2]);
            float e3 = __expf(acc[mt][nt].w - fm[mt][3]);
            acc[mt][nt].x = e0; acc[mt][nt].y = e1;
            acc[mt][nt].z = e2; acc[mt][nt].w = e3;
            rs[mt][0] += e0; rs[mt][1] += e1; rs[mt][2] += e2; rs[mt][3] += e3;
        }
#pragma unroll
    for (int off = 1; off < 16; off <<= 1)
#pragma unroll
        for (int mt = 0; mt < 2; mt++)
#pragma unroll
            for (int r = 0; r < 4; r++)
                rs[mt][r] += __shfl_xor(rs[mt][r], off);
    if (l15 == 0) {
#pragma unroll
        for (int mt = 0; mt < 2; mt++)
#pragma unroll
            for (int r = 0; r < 4; r++)
                red_sum[w][mt * 16 + quad * 4 + r] = rs[mt][r];
    }
    __syncthreads();   // [X2] publish red_sum; ldsP writes (aliasing ldsA) now safe

#pragma unroll
    for (int mt = 0; mt < 2; mt++)
#pragma unroll
        for (int r = 0; r < 4; r++) {
            const int row = mt * 16 + quad * 4 + r;
            float s = 0.f;
#pragma unroll
            for (int j = 0; j < 8; j++) s += red_sum[j][row];
            const float inv = 1.0f / s;
#pragma unroll
            for (int nt = 0; nt < 4; nt++) {
                const int q = w * 64 + nt * 16 + l15;
                float v = (r == 0 ? acc[mt][nt].x : r == 1 ? acc[mt][nt].y
                          : r == 2 ? acc[mt][nt].z : acc[mt][nt].w);
                ldsP[row * PSTRIDE + q] = (_Float16)(v * inv);
            }
        }
    __syncthreads();   // [X3] publish ldsP

    // ---------------- Phase C: awq = P @ Q (no barriers) ----------------
    f32x4 acc2[2][6];
#pragma unroll
    for (int mt = 0; mt < 2; mt++)
#pragma unroll
        for (int nt = 0; nt < 6; nt++)
            acc2[mt][nt] = (f32x4){0.f, 0.f, 0.f, 0.f};

    // lane (quad,l15) of wave w reads QhT[d = w*96 + nt*16 + l15][kc*32 + quad*8]
    const _Float16* cqb = QTb + (size_t)(w * 96 + l15) * LQ + quad * 8;
#pragma unroll
    for (int kc = 0; kc < 16; kc++) {
        f16x8 a0 = *(const f16x8*)&ldsP[(size_t)l15        * PSTRIDE + kc * 32 + quad * 8];
        f16x8 a1 = *(const f16x8*)&ldsP[(size_t)(16 + l15) * PSTRIDE + kc * 32 + quad * 8];
#pragma unroll
        for (int nt = 0; nt < 6; nt++) {
            f16x8 cq = *(const f16x8*)(cqb + (size_t)(nt * 16) * LQ + kc * 32);
            acc2[0][nt] = __builtin_amdgcn_mfma_f32_16x16x32_f16(a0, cq, acc2[0][nt], 0, 0, 0);
            acc2[1][nt] = __builtin_amdgcn_mfma_f32_16x16x32_f16(a1, cq, acc2[1][nt], 0, 0, 0);
        }
    }

    // ---------------- Epilogue: out = ctx * awq ----------------
#pragma unroll
    for (int mt = 0; mt < 2; mt++)
#pragma unroll
        for (int nt = 0; nt < 6; nt++) {
            const int col = w * 96 + nt * 16 + l15;
#pragma unroll
            for (int r = 0; r < 4; r++) {
                const int rl  = mt * 16 + quad * 4 + r;
                const int row = c0 + rl;
                const size_t idx = ((size_t)b * LC + row) * DD + col;
                float v = (r == 0 ? acc2[mt][nt].x : r == 1 ? acc2[mt][nt].y
                          : r == 2 ? acc2[mt][nt].z : acc2[mt][nt].w);
                out[idx] = ctx[idx] * v;
            }
        }
}

extern "C" void kernel_launch(void* const* d_in, const int* in_sizes, int n_in,
                              void* d_out, int out_size, void* d_ws, size_t ws_size,
                              hipStream_t stream) {
    const float* ctx = (const float*)d_in[0];   // [8][2048][768] f32
    const float* q   = (const float*)d_in[1];   // [8][512][768]  f32
    float* out = (float*)d_out;

    const size_t nQ = (size_t)NB * LQ * DD;     // 3,145,728
    _Float16* Qh  = (_Float16*)d_ws;
    _Float16* QhT = Qh + nQ;

    preconvert_q<<<dim3(NB * 96), dim3(256), 0, stream>>>(q, Qh, QhT);
    gated_attn<<<dim3(NB * (LC / 32)), dim3(512), 0, stream>>>(ctx, Qh, QhT, out);
}

// Round 2
// 154.761 us; speedup vs baseline: 1.3292x; 1.3292x over previous
//
#include <hip/hip_runtime.h>

// Problem constants (from reference setup_inputs)
#define NB 8
#define LQ 512
#define LC 2048
#define DD 768

typedef _Float16 f16x8 __attribute__((ext_vector_type(8)));
typedef _Float16 f16x4 __attribute__((ext_vector_type(4)));
typedef float    f32x4 __attribute__((ext_vector_type(4)));

// ---------------------------------------------------------------------------
// K0: convert Q fp32 -> Qh [b][q][d] fp16  AND  QhT [b][d][q] fp16
// ---------------------------------------------------------------------------
__global__ __launch_bounds__(256) void preconvert_q(const float* __restrict__ Q,
                                                    _Float16* __restrict__ Qh,
                                                    _Float16* __restrict__ QhT) {
    __shared__ _Float16 lt[64][68];
    const int blk = blockIdx.x;
    const int b   = blk / 96;
    const int rem = blk % 96;
    const int q0  = (rem / 12) * 64;
    const int d0  = (rem % 12) * 64;
    const int t   = threadIdx.x;
    const int tr  = t >> 4;
    const int tc  = t & 15;

    const float* Qb  = Q  + ((size_t)b * LQ + q0) * DD + d0;
    _Float16*    Qhb = Qh + ((size_t)b * LQ + q0) * DD + d0;

#pragma unroll
    for (int i = 0; i < 4; i++) {
        const int row = i * 16 + tr;
        const int col = tc * 4;
        f32x4 v = *(const f32x4*)(Qb + (size_t)row * DD + col);
        f16x4 h;
        h.x = (_Float16)v.x; h.y = (_Float16)v.y;
        h.z = (_Float16)v.z; h.w = (_Float16)v.w;
        *(f16x4*)(Qhb + (size_t)row * DD + col) = h;
        *(f16x4*)&lt[row][col] = h;
    }
    __syncthreads();

    _Float16* QTb = QhT + ((size_t)b * DD + d0) * LQ + q0;
#pragma unroll
    for (int i = 0; i < 4; i++) {
        const int drow = i * 16 + tr;
        const int qc   = tc * 4;
        f16x4 h;
        h.x = lt[qc + 0][drow];
        h.y = lt[qc + 1][drow];
        h.z = lt[qc + 2][drow];
        h.w = lt[qc + 3][drow];
        *(f16x4*)(QTb + (size_t)drow * LQ + qc) = h;
    }
}

// ---------------------------------------------------------------------------
// Main fused kernel v8: CM=64 c-rows per block -> 8x less L2 Q-traffic.
//
// R1 diagnosis: both prior versions were bound by per-XCD L2 bandwidth.
// Every 32-row block streamed all of Qh+QhT (1.5MB) from L2: 256 blocks/XCD
// x 1.5MB = 384MB at ~4.3TB/s/XCD ~= 89us — matching the measured 85-122us
// while MfmaUtil/VALUBusy/HBM all sat ~10%. Fix: 64-row blocks (grid=256,
// exactly 1 block/CU) quarter the block count -> 48MB/XCD ~= 11us of L2.
//
// LDS (160KB exactly, the gfx950 per-WG max):
//   A-tile [64][768] f16, XOR-swizzled, bytes [0, 98304).  Stays alive
//     through the epilogue: the gate is read from LDS (ctx read ONCE from
//     HBM; no convert kernel, no epilogue global gate read).
//   P-tile [64][512] f16, XOR-swizzled, bytes [98304, 163840).
//   red_max/red_sum [8][64] f32 alias the first 4KB of the P region
//     (consumed into registers before P is written; WAR barrier X3).
//
// Swizzle (both tiles): 16B-slot index s = (c16 & ~7) | ((c16 ^ row) & 7)
// within each row — spreads the stride-1536B/1024B column reads of the MFMA
// A-fragments across 8 bank-groups (2-way residual = free, per m136).
//
// K-loops are barrier-free: B-fragments come straight from L2-resident
// Qh/QhT (4 quads cover one full 64B line per row -> coalesced).
// Barriers: 1 (A staged) + X1/X2 (softmax reductions) + X3 (red WAR)
// + X4 (P published) = 5 total.
// ---------------------------------------------------------------------------
#define CM        64
#define A_SLOTS   96          // 16B slots per A row (768 f16)
#define P_OFF     98304
#define P_SLOTS   64          // 16B slots per P row (512 f16)
#define SMEM_BYTES 163840

__global__ __launch_bounds__(512, 2) void gated_attn(const float* __restrict__ ctx,
                                                     const _Float16* __restrict__ Qh,
                                                     const _Float16* __restrict__ QhT,
                                                     float* __restrict__ out) {
    __shared__ __align__(16) char smem[SMEM_BYTES];
    float (*red_max)[64] = (float (*)[64])(smem + P_OFF);
    float (*red_sum)[64] = (float (*)[64])(smem + P_OFF + 2048);

    const int b    = blockIdx.x & 7;          // XCD-affine batch
    const int c0   = (blockIdx.x >> 3) * CM;
    const int t    = threadIdx.x;
    const int w    = t >> 6;                  // wave 0..7
    const int lane = t & 63;
    const int quad = lane >> 4;
    const int l15  = lane & 15;

    const float*    Cb  = ctx + ((size_t)b * LC + c0) * DD;
    const _Float16* Qhb = Qh  + (size_t)b * LQ * DD;
    const _Float16* QTb = QhT + (size_t)b * DD * LQ;

    const _Float16* bqb = Qhb + (size_t)(w * 64 + l15) * DD + quad * 8;
    const _Float16* cqb = QTb + (size_t)(w * 96 + l15) * LQ + quad * 8;

    // ---------------- Stage A-tile (ctx f32 -> f16, swizzled) ----------------
#pragma unroll
    for (int i = 0; i < 12; i++) {
        const int idx = i * 512 + t;
        const int row = idx / 96;
        const int c16 = idx % 96;
        const float* p = Cb + (size_t)row * DD + c16 * 8;
        f32x4 f0 = *(const f32x4*)p;
        f32x4 f1 = *(const f32x4*)(p + 4);
        f16x8 v;
        v[0] = (_Float16)f0.x; v[1] = (_Float16)f0.y;
        v[2] = (_Float16)f0.z; v[3] = (_Float16)f0.w;
        v[4] = (_Float16)f1.x; v[5] = (_Float16)f1.y;
        v[6] = (_Float16)f1.z; v[7] = (_Float16)f1.w;
        const int s16 = row * A_SLOTS + ((c16 & ~7) | ((c16 ^ row) & 7));
        *(f16x8*)(smem + (size_t)s16 * 16) = v;
    }
    // prefetch phase-A kc=0 B-frags; they complete while staging drains
    f16x8 bq0[4];
#pragma unroll
    for (int nt = 0; nt < 4; nt++)
        bq0[nt] = *(const f16x8*)(bqb + (size_t)(nt * 16) * DD);
    __syncthreads();   // publish ldsA

    // ---------------- Phase A: S = A @ Qh^T (no barriers) ----------------
    f32x4 acc[4][4];
#pragma unroll
    for (int mt = 0; mt < 4; mt++)
#pragma unroll
        for (int nt = 0; nt < 4; nt++)
            acc[mt][nt] = (f32x4){0.f, 0.f, 0.f, 0.f};

#pragma unroll
    for (int kc = 0; kc < 24; kc++) {
        const int c16 = kc * 4 + quad;
        const int sw  = (c16 & ~7) | ((c16 ^ l15) & 7);
        f16x8 a[4];
#pragma unroll
        for (int mt = 0; mt < 4; mt++)
            a[mt] = *(const f16x8*)(smem + (size_t)((mt * 16 + l15) * A_SLOTS + sw) * 16);
        f16x8 bq[4];
#pragma unroll
        for (int nt = 0; nt < 4; nt++)
            bq[nt] = (kc == 0) ? bq0[nt]
                   : *(const f16x8*)(bqb + (size_t)(nt * 16) * DD + kc * 32);
#pragma unroll
        for (int nt = 0; nt < 4; nt++)
#pragma unroll
            for (int mt = 0; mt < 4; mt++)
                acc[mt][nt] = __builtin_amdgcn_mfma_f32_16x16x32_f16(a[mt], bq[nt], acc[mt][nt], 0, 0, 0);
    }

    // prefetch phase-C kc=0 B-frags (complete during softmax)
    f16x8 cq0[6];
#pragma unroll
    for (int nt = 0; nt < 6; nt++)
        cq0[nt] = *(const f16x8*)(cqb + (size_t)(nt * 16) * LQ);

    // ---------------- Softmax over q ----------------
    float rm[4][4];
#pragma unroll
    for (int mt = 0; mt < 4; mt++)
#pragma unroll
        for (int r = 0; r < 4; r++)
            rm[mt][r] = -1e30f;
#pragma unroll
    for (int mt = 0; mt < 4; mt++)
#pragma unroll
        for (int nt = 0; nt < 4; nt++) {
            rm[mt][0] = fmaxf(rm[mt][0], acc[mt][nt].x);
            rm[mt][1] = fmaxf(rm[mt][1], acc[mt][nt].y);
            rm[mt][2] = fmaxf(rm[mt][2], acc[mt][nt].z);
            rm[mt][3] = fmaxf(rm[mt][3], acc[mt][nt].w);
        }
#pragma unroll
    for (int off = 1; off < 16; off <<= 1)
#pragma unroll
        for (int mt = 0; mt < 4; mt++)
#pragma unroll
            for (int r = 0; r < 4; r++)
                rm[mt][r] = fmaxf(rm[mt][r], __shfl_xor(rm[mt][r], off));
    if (l15 == 0) {
#pragma unroll
        for (int mt = 0; mt < 4; mt++)
#pragma unroll
            for (int r = 0; r < 4; r++)
                red_max[w][mt * 16 + quad * 4 + r] = rm[mt][r];
    }
    __syncthreads();   // [X1] publish red_max (all phase-A LDS reads drained)

    float fm[4][4];
#pragma unroll
    for (int mt = 0; mt < 4; mt++)
#pragma unroll
        for (int r = 0; r < 4; r++) {
            const int row = mt * 16 + quad * 4 + r;
            float m0 = fmaxf(fmaxf(red_max[0][row], red_max[1][row]),
                             fmaxf(red_max[2][row], red_max[3][row]));
            float m1 = fmaxf(fmaxf(red_max[4][row], red_max[5][row]),
                             fmaxf(red_max[6][row], red_max[7][row]));
            fm[mt][r] = fmaxf(m0, m1);
        }
    float rs[4][4];
#pragma unroll
    for (int mt = 0; mt < 4; mt++)
#pragma unroll
        for (int r = 0; r < 4; r++)
            rs[mt][r] = 0.f;
#pragma unroll
    for (int mt = 0; mt < 4; mt++)
#pragma unroll
        for (int nt = 0; nt < 4; nt++) {
            float e0 = __expf(acc[mt][nt].x - fm[mt][0]);
            float e1 = __expf(acc[mt][nt].y - fm[mt][1]);
            float e2 = __expf(acc[mt][nt].z - fm[mt][2]);
            float e3 = __expf(acc[mt][nt].w - fm[mt][3]);
            acc[mt][nt].x = e0; acc[mt][nt].y = e1;
            acc[mt][nt].z = e2; acc[mt][nt].w = e3;
            rs[mt][0] += e0; rs[mt][1] += e1; rs[mt][2] += e2; rs[mt][3] += e3;
        }
#pragma unroll
    for (int off = 1; off < 16; off <<= 1)
#pragma unroll
        for (int mt = 0; mt < 4; mt++)
#pragma unroll
            for (int r = 0; r < 4; r++)
                rs[mt][r] += __shfl_xor(rs[mt][r], off);
    if (l15 == 0) {
#pragma unroll
        for (int mt = 0; mt < 4; mt++)
#pragma unroll
            for (int r = 0; r < 4; r++)
                red_sum[w][mt * 16 + quad * 4 + r] = rs[mt][r];
    }
    __syncthreads();   // [X2] publish red_sum

#pragma unroll
    for (int mt = 0; mt < 4; mt++)
#pragma unroll
        for (int r = 0; r < 4; r++) {
            const int row = mt * 16 + quad * 4 + r;
            float s = 0.f;
#pragma unroll
            for (int j = 0; j < 8; j++) s += red_sum[j][row];
            const float inv = 1.0f / s;
#pragma unroll
            for (int nt = 0; nt < 4; nt++) {
                acc[mt][nt].x = (r == 0) ? acc[mt][nt].x * inv : acc[mt][nt].x;
                acc[mt][nt].y = (r == 1) ? acc[mt][nt].y * inv : acc[mt][nt].y;
                acc[mt][nt].z = (r == 2) ? acc[mt][nt].z * inv : acc[mt][nt].z;
                acc[mt][nt].w = (r == 3) ? acc[mt][nt].w * inv : acc[mt][nt].w;
            }
        }
    __syncthreads();   // [X3] red region reads drained; P writes may overwrite it

    // write P (f16, swizzled)
#pragma unroll
    for (int mt = 0; mt < 4; mt++)
#pragma unroll
        for (int r = 0; r < 4; r++) {
            const int row = mt * 16 + quad * 4 + r;
#pragma unroll
            for (int nt = 0; nt < 4; nt++) {
                const int q = w * 64 + nt * 16 + l15;
                float v = (r == 0 ? acc[mt][nt].x : r == 1 ? acc[mt][nt].y
                          : r == 2 ? acc[mt][nt].z : acc[mt][nt].w);
                const int c16 = q >> 3;
                const int s16 = row * P_SLOTS + ((c16 & ~7) | ((c16 ^ row) & 7));
                *(_Float16*)(smem + P_OFF + (size_t)s16 * 16 + (q & 7) * 2) = (_Float16)v;
            }
        }
    __syncthreads();   // [X4] publish P

    // ---------------- Phase C: awq = P @ Q (no barriers) ----------------
    f32x4 acc2[4][6];
#pragma unroll
    for (int mt = 0; mt < 4; mt++)
#pragma unroll
        for (int nt = 0; nt < 6; nt++)
            acc2[mt][nt] = (f32x4){0.f, 0.f, 0.f, 0.f};

#pragma unroll
    for (int kc = 0; kc < 16; kc++) {
        const int c16 = kc * 4 + quad;
        const int sw  = (c16 & ~7) | ((c16 ^ l15) & 7);
        f16x8 pf[4];
#pragma unroll
        for (int mt = 0; mt < 4; mt++)
            pf[mt] = *(const f16x8*)(smem + P_OFF + (size_t)((mt * 16 + l15) * P_SLOTS + sw) * 16);
        f16x8 cq[6];
#pragma unroll
        for (int nt = 0; nt < 6; nt++)
            cq[nt] = (kc == 0) ? cq0[nt]
                   : *(const f16x8*)(cqb + (size_t)(nt * 16) * LQ + kc * 32);
#pragma unroll
        for (int nt = 0; nt < 6; nt++)
#pragma unroll
            for (int mt = 0; mt < 4; mt++)
                acc2[mt][nt] = __builtin_amdgcn_mfma_f32_16x16x32_f16(pf[mt], cq[nt], acc2[mt][nt], 0, 0, 0);
    }

    // ---------------- Epilogue: out = gate(LDS A-tile) * awq ----------------
#pragma unroll
    for (int mt = 0; mt < 4; mt++)
#pragma unroll
        for (int nt = 0; nt < 6; nt++) {
            const int col = w * 96 + nt * 16 + l15;
            const int c16 = col >> 3;
            const int sub = col & 7;
#pragma unroll
            for (int r = 0; r < 4; r++) {
                const int rl  = mt * 16 + quad * 4 + r;
                const int s16 = rl * A_SLOTS + ((c16 & ~7) | ((c16 ^ rl) & 7));
                const float g = (float)*(const _Float16*)(smem + (size_t)s16 * 16 + sub * 2);
                float v = (r == 0 ? acc2[mt][nt].x : r == 1 ? acc2[mt][nt].y
                          : r == 2 ? acc2[mt][nt].z : acc2[mt][nt].w);
                out[((size_t)b * LC + c0 + rl) * DD + col] = g * v;
            }
        }
}

extern "C" void kernel_launch(void* const* d_in, const int* in_sizes, int n_in,
                              void* d_out, int out_size, void* d_ws, size_t ws_size,
                              hipStream_t stream) {
    const float* ctx = (const float*)d_in[0];   // [8][2048][768] f32
    const float* q   = (const float*)d_in[1];   // [8][512][768]  f32
    float* out = (float*)d_out;

    const size_t nQ = (size_t)NB * LQ * DD;     // 3,145,728
    _Float16* Qh  = (_Float16*)d_ws;
    _Float16* QhT = Qh + nQ;

    preconvert_q<<<dim3(NB * 96), dim3(256), 0, stream>>>(q, Qh, QhT);
    gated_attn<<<dim3(NB * (LC / CM)), dim3(512), 0, stream>>>(ctx, Qh, QhT, out);
}

// Round 3
// 152.394 us; speedup vs baseline: 1.3498x; 1.0155x over previous
//
#include <hip/hip_runtime.h>

// Problem constants (from reference setup_inputs)
#define NB 8
#define LQ 512
#define LC 2048
#define DD 768

typedef _Float16 f16x8 __attribute__((ext_vector_type(8)));
typedef _Float16 f16x4 __attribute__((ext_vector_type(4)));
typedef float    f32x4 __attribute__((ext_vector_type(4)));

// ---------------------------------------------------------------------------
// K0: convert Q fp32 -> Qh [b][q][d] fp16  AND  QhT [b][d][q] fp16
// ---------------------------------------------------------------------------
__global__ __launch_bounds__(256) void preconvert_q(const float* __restrict__ Q,
                                                    _Float16* __restrict__ Qh,
                                                    _Float16* __restrict__ QhT) {
    __shared__ _Float16 lt[64][68];
    const int blk = blockIdx.x;
    const int b   = blk / 96;
    const int rem = blk % 96;
    const int q0  = (rem / 12) * 64;
    const int d0  = (rem % 12) * 64;
    const int t   = threadIdx.x;
    const int tr  = t >> 4;
    const int tc  = t & 15;

    const float* Qb  = Q  + ((size_t)b * LQ + q0) * DD + d0;
    _Float16*    Qhb = Qh + ((size_t)b * LQ + q0) * DD + d0;

#pragma unroll
    for (int i = 0; i < 4; i++) {
        const int row = i * 16 + tr;
        const int col = tc * 4;
        f32x4 v = *(const f32x4*)(Qb + (size_t)row * DD + col);
        f16x4 h;
        h.x = (_Float16)v.x; h.y = (_Float16)v.y;
        h.z = (_Float16)v.z; h.w = (_Float16)v.w;
        *(f16x4*)(Qhb + (size_t)row * DD + col) = h;
        *(f16x4*)&lt[row][col] = h;
    }
    __syncthreads();

    _Float16* QTb = QhT + ((size_t)b * DD + d0) * LQ + q0;
#pragma unroll
    for (int i = 0; i < 4; i++) {
        const int drow = i * 16 + tr;
        const int qc   = tc * 4;
        f16x4 h;
        h.x = lt[qc + 0][drow];
        h.y = lt[qc + 1][drow];
        h.z = lt[qc + 2][drow];
        h.w = lt[qc + 3][drow];
        *(f16x4*)(QTb + (size_t)drow * LQ + qc) = h;
    }
}

// ---------------------------------------------------------------------------
// Main fused kernel v9: v8 + explicit software pipelining.
//
// R2 diagnosis: latency-bound (all pipes <15%; ideal-pipeline cost ~20us vs
// 71us measured). VGPR_Count=124 of a 256 cap -> compiler hoisted loads only
// ~1 iteration deep; the 4 L2 B-frag loads (~200-300cy) stall every kc.
//
// v9: ring-3 register prefetch for global B-frags (lookahead 2 iterations),
// ring-2 for LDS A/P-frags, in both K-loops. Phase-C kc=0/1 B-frags issued
// BEFORE softmax (latency hides under the VALU reduction). Phase-A kc=0/1
// B-frags issued before the staging stores (completed for free by the
// barrier's vmcnt drain). s_setprio(1) around each MFMA cluster (waves drift
// in the barrier-free K-loops -> role diversity).
//
// LDS map unchanged from v8 (160KB): A [64][768] f16 swizzled [0,98304),
// P [64][512] f16 swizzled [98304,163840), red aliases P head (X3 WAR).
// ---------------------------------------------------------------------------
#define CM        64
#define A_SLOTS   96          // 16B slots per A row (768 f16)
#define P_OFF     98304
#define P_SLOTS   64          // 16B slots per P row (512 f16)
#define SMEM_BYTES 163840

__global__ __launch_bounds__(512, 2) void gated_attn(const float* __restrict__ ctx,
                                                     const _Float16* __restrict__ Qh,
                                                     const _Float16* __restrict__ QhT,
                                                     float* __restrict__ out) {
    __shared__ __align__(16) char smem[SMEM_BYTES];
    float (*red_max)[64] = (float (*)[64])(smem + P_OFF);
    float (*red_sum)[64] = (float (*)[64])(smem + P_OFF + 2048);

    const int b    = blockIdx.x & 7;          // XCD-affine batch
    const int c0   = (blockIdx.x >> 3) * CM;
    const int t    = threadIdx.x;
    const int w    = t >> 6;                  // wave 0..7
    const int lane = t & 63;
    const int quad = lane >> 4;
    const int l15  = lane & 15;

    const float*    Cb  = ctx + ((size_t)b * LC + c0) * DD;
    const _Float16* Qhb = Qh  + (size_t)b * LQ * DD;
    const _Float16* QTb = QhT + (size_t)b * DD * LQ;

    const _Float16* bqb = Qhb + (size_t)(w * 64 + l15) * DD + quad * 8;
    const _Float16* cqb = QTb + (size_t)(w * 96 + l15) * LQ + quad * 8;

    // -------- Phase-A B-frag preload (kc=0,1): issued FIRST in program order
    // so the staging barrier's vmcnt drain completes them for free.
    f16x8 bP[3][4];
#pragma unroll
    for (int s = 0; s < 2; s++)
#pragma unroll
        for (int nt = 0; nt < 4; nt++)
            bP[s][nt] = *(const f16x8*)(bqb + (size_t)(nt * 16) * DD + s * 32);

    // ---------------- Stage A-tile (ctx f32 -> f16, swizzled) ----------------
#pragma unroll
    for (int i = 0; i < 12; i++) {
        const int idx = i * 512 + t;
        const int row = idx / 96;
        const int c16 = idx % 96;
        const float* p = Cb + (size_t)row * DD + c16 * 8;
        f32x4 f0 = *(const f32x4*)p;
        f32x4 f1 = *(const f32x4*)(p + 4);
        f16x8 v;
        v[0] = (_Float16)f0.x; v[1] = (_Float16)f0.y;
        v[2] = (_Float16)f0.z; v[3] = (_Float16)f0.w;
        v[4] = (_Float16)f1.x; v[5] = (_Float16)f1.y;
        v[6] = (_Float16)f1.z; v[7] = (_Float16)f1.w;
        const int s16 = row * A_SLOTS + ((c16 & ~7) | ((c16 ^ row) & 7));
        *(f16x8*)(smem + (size_t)s16 * 16) = v;
    }
    __syncthreads();   // publish ldsA (drains bP[0..1] loads too)

    // ---------------- Phase A: S = A @ Qh^T (no barriers, pipelined) ---------
    f32x4 acc[4][4];
#pragma unroll
    for (int mt = 0; mt < 4; mt++)
#pragma unroll
        for (int nt = 0; nt < 4; nt++)
            acc[mt][nt] = (f32x4){0.f, 0.f, 0.f, 0.f};

    f16x8 aP[2][4];
    {
        const int sw0 = (quad & ~7) | ((quad ^ l15) & 7);   // kc=0, c16=quad
#pragma unroll
        for (int mt = 0; mt < 4; mt++)
            aP[0][mt] = *(const f16x8*)(smem + (size_t)((mt * 16 + l15) * A_SLOTS + sw0) * 16);
    }

#pragma unroll
    for (int kc = 0; kc < 24; kc++) {
        if (kc + 2 < 24) {
#pragma unroll
            for (int nt = 0; nt < 4; nt++)
                bP[(kc + 2) % 3][nt] = *(const f16x8*)(bqb + (size_t)(nt * 16) * DD + (kc + 2) * 32);
        }
        if (kc + 1 < 24) {
            const int c16 = (kc + 1) * 4 + quad;
            const int sw  = (c16 & ~7) | ((c16 ^ l15) & 7);
#pragma unroll
            for (int mt = 0; mt < 4; mt++)
                aP[(kc + 1) & 1][mt] = *(const f16x8*)(smem + (size_t)((mt * 16 + l15) * A_SLOTS + sw) * 16);
        }
        __builtin_amdgcn_s_setprio(1);
#pragma unroll
        for (int nt = 0; nt < 4; nt++)
#pragma unroll
            for (int mt = 0; mt < 4; mt++)
                acc[mt][nt] = __builtin_amdgcn_mfma_f32_16x16x32_f16(aP[kc & 1][mt], bP[kc % 3][nt], acc[mt][nt], 0, 0, 0);
        __builtin_amdgcn_s_setprio(0);
    }

    // -------- Phase-C B-frag preload (kc=0,1): latency hides under softmax --
    f16x8 cP[3][6];
#pragma unroll
    for (int s = 0; s < 2; s++)
#pragma unroll
        for (int nt = 0; nt < 6; nt++)
            cP[s][nt] = *(const f16x8*)(cqb + (size_t)(nt * 16) * LQ + s * 32);

    // ---------------- Softmax over q ----------------
    float rm[4][4];
#pragma unroll
    for (int mt = 0; mt < 4; mt++)
#pragma unroll
        for (int r = 0; r < 4; r++)
            rm[mt][r] = -1e30f;
#pragma unroll
    for (int mt = 0; mt < 4; mt++)
#pragma unroll
        for (int nt = 0; nt < 4; nt++) {
            rm[mt][0] = fmaxf(rm[mt][0], acc[mt][nt].x);
            rm[mt][1] = fmaxf(rm[mt][1], acc[mt][nt].y);
            rm[mt][2] = fmaxf(rm[mt][2], acc[mt][nt].z);
            rm[mt][3] = fmaxf(rm[mt][3], acc[mt][nt].w);
        }
#pragma unroll
    for (int off = 1; off < 16; off <<= 1)
#pragma unroll
        for (int mt = 0; mt < 4; mt++)
#pragma unroll
            for (int r = 0; r < 4; r++)
                rm[mt][r] = fmaxf(rm[mt][r], __shfl_xor(rm[mt][r], off));
    if (l15 == 0) {
#pragma unroll
        for (int mt = 0; mt < 4; mt++)
#pragma unroll
            for (int r = 0; r < 4; r++)
                red_max[w][mt * 16 + quad * 4 + r] = rm[mt][r];
    }
    __syncthreads();   // [X1] publish red_max (all phase-A LDS reads drained)

    float fm[4][4];
#pragma unroll
    for (int mt = 0; mt < 4; mt++)
#pragma unroll
        for (int r = 0; r < 4; r++) {
            const int row = mt * 16 + quad * 4 + r;
            float m0 = fmaxf(fmaxf(red_max[0][row], red_max[1][row]),
                             fmaxf(red_max[2][row], red_max[3][row]));
            float m1 = fmaxf(fmaxf(red_max[4][row], red_max[5][row]),
                             fmaxf(red_max[6][row], red_max[7][row]));
            fm[mt][r] = fmaxf(m0, m1);
        }
    float rs[4][4];
#pragma unroll
    for (int mt = 0; mt < 4; mt++)
#pragma unroll
        for (int r = 0; r < 4; r++)
            rs[mt][r] = 0.f;
#pragma unroll
    for (int mt = 0; mt < 4; mt++)
#pragma unroll
        for (int nt = 0; nt < 4; nt++) {
            float e0 = __expf(acc[mt][nt].x - fm[mt][0]);
            float e1 = __expf(acc[mt][nt].y - fm[mt][1]);
            float e2 = __expf(acc[mt][nt].z - fm[mt][2]);
            float e3 = __expf(acc[mt][nt].w - fm[mt][3]);
            acc[mt][nt].x = e0; acc[mt][nt].y = e1;
            acc[mt][nt].z = e2; acc[mt][nt].w = e3;
            rs[mt][0] += e0; rs[mt][1] += e1; rs[mt][2] += e2; rs[mt][3] += e3;
        }
#pragma unroll
    for (int off = 1; off < 16; off <<= 1)
#pragma unroll
        for (int mt = 0; mt < 4; mt++)
#pragma unroll
            for (int r = 0; r < 4; r++)
                rs[mt][r] += __shfl_xor(rs[mt][r], off);
    if (l15 == 0) {
#pragma unroll
        for (int mt = 0; mt < 4; mt++)
#pragma unroll
            for (int r = 0; r < 4; r++)
                red_sum[w][mt * 16 + quad * 4 + r] = rs[mt][r];
    }
    __syncthreads();   // [X2] publish red_sum

#pragma unroll
    for (int mt = 0; mt < 4; mt++)
#pragma unroll
        for (int r = 0; r < 4; r++) {
            const int row = mt * 16 + quad * 4 + r;
            float s = 0.f;
#pragma unroll
            for (int j = 0; j < 8; j++) s += red_sum[j][row];
            const float inv = 1.0f / s;
#pragma unroll
            for (int nt = 0; nt < 4; nt++) {
                acc[mt][nt].x = (r == 0) ? acc[mt][nt].x * inv : acc[mt][nt].x;
                acc[mt][nt].y = (r == 1) ? acc[mt][nt].y * inv : acc[mt][nt].y;
                acc[mt][nt].z = (r == 2) ? acc[mt][nt].z * inv : acc[mt][nt].z;
                acc[mt][nt].w = (r == 3) ? acc[mt][nt].w * inv : acc[mt][nt].w;
            }
        }
    __syncthreads();   // [X3] red region reads drained; P writes may overwrite it

    // write P (f16, swizzled)
#pragma unroll
    for (int mt = 0; mt < 4; mt++)
#pragma unroll
        for (int r = 0; r < 4; r++) {
            const int row = mt * 16 + quad * 4 + r;
#pragma unroll
            for (int nt = 0; nt < 4; nt++) {
                const int q = w * 64 + nt * 16 + l15;
                float v = (r == 0 ? acc[mt][nt].x : r == 1 ? acc[mt][nt].y
                          : r == 2 ? acc[mt][nt].z : acc[mt][nt].w);
                const int c16 = q >> 3;
                const int s16 = row * P_SLOTS + ((c16 & ~7) | ((c16 ^ row) & 7));
                *(_Float16*)(smem + P_OFF + (size_t)s16 * 16 + (q & 7) * 2) = (_Float16)v;
            }
        }
    __syncthreads();   // [X4] publish P

    // ---------------- Phase C: awq = P @ Q (no barriers, pipelined) ----------
    f32x4 acc2[4][6];
#pragma unroll
    for (int mt = 0; mt < 4; mt++)
#pragma unroll
        for (int nt = 0; nt < 6; nt++)
            acc2[mt][nt] = (f32x4){0.f, 0.f, 0.f, 0.f};

    f16x8 pP[2][4];
    {
        const int sw0 = (quad & ~7) | ((quad ^ l15) & 7);   // kc=0, c16=quad
#pragma unroll
        for (int mt = 0; mt < 4; mt++)
            pP[0][mt] = *(const f16x8*)(smem + P_OFF + (size_t)((mt * 16 + l15) * P_SLOTS + sw0) * 16);
    }

#pragma unroll
    for (int kc = 0; kc < 16; kc++) {
        if (kc + 2 < 16) {
#pragma unroll
            for (int nt = 0; nt < 6; nt++)
                cP[(kc + 2) % 3][nt] = *(const f16x8*)(cqb + (size_t)(nt * 16) * LQ + (kc + 2) * 32);
        }
        if (kc + 1 < 16) {
            const int c16 = (kc + 1) * 4 + quad;
            const int sw  = (c16 & ~7) | ((c16 ^ l15) & 7);
#pragma unroll
            for (int mt = 0; mt < 4; mt++)
                pP[(kc + 1) & 1][mt] = *(const f16x8*)(smem + P_OFF + (size_t)((mt * 16 + l15) * P_SLOTS + sw) * 16);
        }
        __builtin_amdgcn_s_setprio(1);
#pragma unroll
        for (int nt = 0; nt < 6; nt++)
#pragma unroll
            for (int mt = 0; mt < 4; mt++)
                acc2[mt][nt] = __builtin_amdgcn_mfma_f32_16x16x32_f16(pP[kc & 1][mt], cP[kc % 3][nt], acc2[mt][nt], 0, 0, 0);
        __builtin_amdgcn_s_setprio(0);
    }

    // ---------------- Epilogue: out = gate(LDS A-tile) * awq ----------------
#pragma unroll
    for (int mt = 0; mt < 4; mt++)
#pragma unroll
        for (int nt = 0; nt < 6; nt++) {
            const int col = w * 96 + nt * 16 + l15;
            const int c16 = col >> 3;
            const int sub = col & 7;
#pragma unroll
            for (int r = 0; r < 4; r++) {
                const int rl  = mt * 16 + quad * 4 + r;
                const int s16 = rl * A_SLOTS + ((c16 & ~7) | ((c16 ^ rl) & 7));
                const float g = (float)*(const _Float16*)(smem + (size_t)s16 * 16 + sub * 2);
                float v = (r == 0 ? acc2[mt][nt].x : r == 1 ? acc2[mt][nt].y
                          : r == 2 ? acc2[mt][nt].z : acc2[mt][nt].w);
                out[((size_t)b * LC + c0 + rl) * DD + col] = g * v;
            }
        }
}

extern "C" void kernel_launch(void* const* d_in, const int* in_sizes, int n_in,
                              void* d_out, int out_size, void* d_ws, size_t ws_size,
                              hipStream_t stream) {
    const float* ctx = (const float*)d_in[0];   // [8][2048][768] f32
    const float* q   = (const float*)d_in[1];   // [8][512][768]  f32
    float* out = (float*)d_out;

    const size_t nQ = (size_t)NB * LQ * DD;     // 3,145,728
    _Float16* Qh  = (_Float16*)d_ws;
    _Float16* QhT = Qh + nQ;

    preconvert_q<<<dim3(NB * 96), dim3(256), 0, stream>>>(q, Qh, QhT);
    gated_attn<<<dim3(NB * (LC / CM)), dim3(512), 0, stream>>>(ctx, Qh, QhT, out);
}